// Round 1
// baseline (477.936 us; speedup 1.0000x reference)
//
#include <hip/hip_runtime.h>
#include <hip/hip_bf16.h>

typedef __attribute__((ext_vector_type(8))) short short8;
typedef __attribute__((ext_vector_type(4))) float f32x4;

#define DEVINL static __device__ __forceinline__

DEVINL unsigned short f2b(float f) {
  __hip_bfloat16 h = __float2bfloat16(f);
  return __builtin_bit_cast(unsigned short, h);
}

DEVINL short8 lds_ld8(const unsigned short* p) {
  return *reinterpret_cast<const short8*>(p);
}

// ============ GEMM + bias: C[M,N] = A[M,K](f32) @ W[K,N](f32) + bias[N] ======
// MODE 0: bf16 out, layout [B,H,S,64]   (Q,K split heads)
// MODE 1: f32  out, layout [M,N]        (final projection -> d_out)
// MODE 2: bf16 out, layout [B,H,64,S]   (V transposed heads, k-major for PV)
template<int MODE>
__global__ __launch_bounds__(256)
void gemm_bias_kernel(const float* __restrict__ A, const float* __restrict__ W,
                      const float* __restrict__ bias, void* __restrict__ outp,
                      int M, int N, int K)
{
  constexpr int BK = 32;
  __shared__ __align__(16) unsigned short Asm[128][BK + 8]; // [m][k] bf16, +8 pad
  __shared__ __align__(16) unsigned short Bsm[128][BK + 8]; // [n][k] bf16 (W^T tile)

  const int tid = threadIdx.x;
  const int lane = tid & 63;
  const int wid = tid >> 6;
  const int l15 = lane & 15;
  const int lg  = lane >> 4;
  const long bm = (long)blockIdx.y * 128;
  const long bn = (long)blockIdx.x * 128;
  const int wm = (wid >> 1) * 64;
  const int wn = (wid & 1) * 64;

  f32x4 acc[4][4] = {};

  for (int kt = 0; kt < K; kt += BK) {
    // stage A tile 128x32: row-major, fp32 -> bf16
    #pragma unroll
    for (int i = 0; i < 4; ++i) {
      int task = tid + 256 * i;       // 0..1023
      int r  = task >> 3;             // 0..127
      int c4 = (task & 7) << 2;       // 0..28
      const float4 v = *reinterpret_cast<const float4*>(A + (bm + r) * K + kt + c4);
      ushort4 h;
      h.x = f2b(v.x); h.y = f2b(v.y); h.z = f2b(v.z); h.w = f2b(v.w);
      *reinterpret_cast<ushort4*>(&Asm[r][c4]) = h;
    }
    // stage W tile 32x128 transposed -> Bsm[n][k]; coalesced loads along n
    #pragma unroll
    for (int i = 0; i < 4; ++i) {
      int task = tid + 256 * i;
      int n  = task & 127;
      int kq = (task >> 7) << 2;      // 0,4,...,28
      const float* wp = W + (long)(kt + kq) * N + bn + n;
      ushort4 h;
      h.x = f2b(wp[0]);
      h.y = f2b(wp[N]);
      h.z = f2b(wp[2 * N]);
      h.w = f2b(wp[3 * N]);
      *reinterpret_cast<ushort4*>(&Bsm[n][kq]) = h;
    }
    __syncthreads();

    short8 af[4], bf[4];
    #pragma unroll
    for (int m = 0; m < 4; ++m)
      af[m] = lds_ld8(&Asm[wm + m*16 + l15][lg*8]);
    #pragma unroll
    for (int n = 0; n < 4; ++n)
      bf[n] = lds_ld8(&Bsm[wn + n*16 + l15][lg*8]);
    #pragma unroll
    for (int m = 0; m < 4; ++m) {
      #pragma unroll
      for (int n = 0; n < 4; ++n)
        acc[m][n] = __builtin_amdgcn_mfma_f32_16x16x32_bf16(af[m], bf[n], acc[m][n], 0, 0, 0);
    }
    __syncthreads();
  }

  float bv[4];
  #pragma unroll
  for (int n = 0; n < 4; ++n) bv[n] = bias[bn + wn + n*16 + l15];

  if (MODE == 1) {
    float* out = (float*)outp;
    #pragma unroll
    for (int m = 0; m < 4; ++m) {
      #pragma unroll
      for (int r = 0; r < 4; ++r) {
        long row = bm + wm + m*16 + lg*4 + r;
        #pragma unroll
        for (int n = 0; n < 4; ++n)
          out[row * N + bn + wn + n*16 + l15] = acc[m][n][r] + bv[n];
      }
    }
  } else if (MODE == 0) {
    unsigned short* out = (unsigned short*)outp;
    #pragma unroll
    for (int m = 0; m < 4; ++m) {
      #pragma unroll
      for (int r = 0; r < 4; ++r) {
        long row = bm + wm + m*16 + lg*4 + r;   // flat B*S row
        long b = row >> 11, s = row & 2047;
        #pragma unroll
        for (int n = 0; n < 4; ++n) {
          long col = bn + wn + n*16 + l15;
          long h = col >> 6, dk = col & 63;
          out[((((b << 4) + h) << 11) + s) * 64 + dk] = f2b(acc[m][n][r] + bv[n]);
        }
      }
    }
  } else { // MODE 2: [B,H,64,S], pack 4 consecutive s per store
    unsigned short* out = (unsigned short*)outp;
    #pragma unroll
    for (int m = 0; m < 4; ++m) {
      long row0 = bm + wm + m*16 + lg*4;
      long b = row0 >> 11, s0 = row0 & 2047;
      #pragma unroll
      for (int n = 0; n < 4; ++n) {
        long col = bn + wn + n*16 + l15;
        long h = col >> 6, dk = col & 63;
        ushort4 hv;
        hv.x = f2b(acc[m][n][0] + bv[n]);
        hv.y = f2b(acc[m][n][1] + bv[n]);
        hv.z = f2b(acc[m][n][2] + bv[n]);
        hv.w = f2b(acc[m][n][3] + bv[n]);
        *reinterpret_cast<ushort4*>(&out[((((b << 4) + h) << 6) + dk) * 2048 + s0]) = hv;
      }
    }
  }
}

// ============ Flash attention with banded local-window enhancement ===========
// Q,K: [B,H,S,64] bf16;  Vth: [B,H,64,S] bf16;  O: [B,S,1024] f32
// scores = (QK^T)/8, doubled where |i-j|<=4, softmax over full row, O = P V.
__global__ __launch_bounds__(256)
void attn_kernel(const unsigned short* __restrict__ Q,
                 const unsigned short* __restrict__ Kh,
                 const unsigned short* __restrict__ Vth,
                 float* __restrict__ O)
{
  __shared__ __align__(16) unsigned short Ksm[64 * 64];   // XOR-swizzled [kv][d]
  __shared__ __align__(16) unsigned short Vsm[64][72];    // [d][kv], padded
  __shared__ __align__(16) unsigned short Psm[4][16][72]; // per-wave P, padded

  const int tid = threadIdx.x;
  const int lane = tid & 63;
  const int w = tid >> 6;
  const int l15 = lane & 15;
  const int lg  = lane >> 4;
  const int bh = blockIdx.y;          // b*16 + h
  const int qb = blockIdx.x * 64;
  const long base = (long)bh * 2048 * 64;

  // Q fragments held in registers: wave w owns q rows [qb+16w, qb+16w+15]
  short8 aq[2];
  {
    const unsigned short* qp = Q + base + (long)(qb + w*16 + l15) * 64 + lg*8;
    aq[0] = *reinterpret_cast<const short8*>(qp);
    aq[1] = *reinterpret_cast<const short8*>(qp + 32);
  }

  f32x4 oacc[4] = {};
  float mrow[4], lrow[4];
  #pragma unroll
  for (int r = 0; r < 4; ++r) { mrow[r] = -1e30f; lrow[r] = 0.f; }

  for (int kvt = 0; kvt < 2048; kvt += 64) {
    // ---- stage K tile (rows XOR-swizzled to spread banks) ----
    #pragma unroll
    for (int c = 0; c < 2; ++c) {
      int e = (tid + 256 * c) * 8;          // element offset in 64x64 tile
      int row = e >> 6;
      int colb = (e & 63) * 2;
      uint4 v = *reinterpret_cast<const uint4*>(Kh + base + (long)kvt * 64 + e);
      int dst = (row * 128 + colb) ^ ((row & 7) << 4);
      *reinterpret_cast<uint4*>(reinterpret_cast<char*>(Ksm) + dst) = v;
    }
    // ---- stage V^T tile: global [d][s] rows -> Vsm[d][kv] ----
    {
      int dr = tid >> 2;                    // 0..63 (d)
      int ch = (tid & 3) * 16;              // kv chunk
      const unsigned short* vp = Vth + (long)bh * 64 * 2048 + (long)dr * 2048 + kvt + ch;
      uint4 v0 = *reinterpret_cast<const uint4*>(vp);
      uint4 v1 = *reinterpret_cast<const uint4*>(vp + 8);
      *reinterpret_cast<uint4*>(&Vsm[dr][ch]) = v0;
      *reinterpret_cast<uint4*>(&Vsm[dr][ch + 8]) = v1;
    }
    __syncthreads();

    // ---- S = Q @ K^T : C frag n -> kv cols [16n,16n+15] ----
    f32x4 sacc[4] = {};
    #pragma unroll
    for (int n = 0; n < 4; ++n) {
      #pragma unroll
      for (int kc = 0; kc < 2; ++kc) {
        int row = n * 16 + l15;
        int src = (row * 128 + (kc * 32 + lg * 8) * 2) ^ ((row & 7) << 4);
        short8 bk = *reinterpret_cast<const short8*>(reinterpret_cast<char*>(Ksm) + src);
        sacc[n] = __builtin_amdgcn_mfma_f32_16x16x32_bf16(aq[kc], bk, sacc[n], 0, 0, 0);
      }
    }

    // ---- scale + banded enhancement (only near-diagonal tiles) ----
    const bool band_near = (kvt + 67 >= qb) && (kvt <= qb + 67);
    #pragma unroll
    for (int n = 0; n < 4; ++n) {
      #pragma unroll
      for (int r = 0; r < 4; ++r) {
        float s = sacc[n][r] * 0.125f;
        if (band_near) {
          int d = (qb + w*16 + lg*4 + r) - (kvt + n*16 + l15);
          if (d >= -4 && d <= 4) s *= 2.f;
        }
        sacc[n][r] = s;
      }
    }

    // ---- online softmax (row = q, spread over 16-lane group x 4 frags) ----
    float corr[4];
    #pragma unroll
    for (int r = 0; r < 4; ++r) {
      float t = fmaxf(fmaxf(sacc[0][r], sacc[1][r]), fmaxf(sacc[2][r], sacc[3][r]));
      #pragma unroll
      for (int off = 1; off < 16; off <<= 1) t = fmaxf(t, __shfl_xor(t, off));
      float mnew = fmaxf(mrow[r], t);
      corr[r] = expf(mrow[r] - mnew);
      mrow[r] = mnew;
    }
    float rsum[4] = {0.f, 0.f, 0.f, 0.f};
    #pragma unroll
    for (int n = 0; n < 4; ++n) {
      #pragma unroll
      for (int r = 0; r < 4; ++r) {
        float p = expf(sacc[n][r] - mrow[r]);
        sacc[n][r] = p;
        rsum[r] += p;
      }
    }
    #pragma unroll
    for (int r = 0; r < 4; ++r) {
      float t = rsum[r];
      #pragma unroll
      for (int off = 1; off < 16; off <<= 1) t += __shfl_xor(t, off);
      lrow[r] = lrow[r] * corr[r] + t;
      #pragma unroll
      for (int nd = 0; nd < 4; ++nd) oacc[nd][r] *= corr[r];
    }

    // ---- P -> bf16 via per-wave LDS (layout change for PV A-operand) ----
    #pragma unroll
    for (int n = 0; n < 4; ++n) {
      #pragma unroll
      for (int r = 0; r < 4; ++r)
        Psm[w][lg*4 + r][n*16 + l15] = f2b(sacc[n][r]);
    }

    // ---- O += P @ V ----
    #pragma unroll
    for (int kc = 0; kc < 2; ++kc) {
      short8 pf = *reinterpret_cast<const short8*>(&Psm[w][l15][kc*32 + lg*8]);
      #pragma unroll
      for (int nd = 0; nd < 4; ++nd) {
        short8 vf = *reinterpret_cast<const short8*>(&Vsm[nd*16 + l15][kc*32 + lg*8]);
        oacc[nd] = __builtin_amdgcn_mfma_f32_16x16x32_bf16(pf, vf, oacc[nd], 0, 0, 0);
      }
    }
    __syncthreads();
  }

  // ---- epilogue: normalize, write merged-head fp32 [B,S,1024] ----
  const int b = bh >> 4, h = bh & 15;
  #pragma unroll
  for (int r = 0; r < 4; ++r) {
    float inv = 1.f / lrow[r];
    float* op = O + ((long)(b * 2048 + qb + w*16 + lg*4 + r) << 10) + h * 64;
    #pragma unroll
    for (int nd = 0; nd < 4; ++nd)
      op[nd*16 + l15] = oacc[nd][r] * inv;
  }
}

extern "C" void kernel_launch(void* const* d_in, const int* in_sizes, int n_in,
                              void* d_out, int out_size, void* d_ws, size_t ws_size,
                              hipStream_t stream)
{
  const float* query = (const float*)d_in[0];
  const float* key_  = (const float*)d_in[1];
  const float* value = (const float*)d_in[2];
  const float* Wq = (const float*)d_in[3];
  const float* bq = (const float*)d_in[4];
  const float* Wk = (const float*)d_in[5];
  const float* bk = (const float*)d_in[6];
  const float* Wv = (const float*)d_in[7];
  const float* bv = (const float*)d_in[8];
  const float* Wo = (const float*)d_in[9];
  const float* bo = (const float*)d_in[10];

  // workspace layout (80 MB total):
  //   qh [B,H,S,64] bf16 16MB | kh 16MB | vt [B,H,64,S] bf16 16MB | attn f32 32MB
  char* ws = (char*)d_ws;
  unsigned short* qh = (unsigned short*)(ws);
  unsigned short* kh = (unsigned short*)(ws + (size_t)16777216);
  unsigned short* vt = (unsigned short*)(ws + (size_t)2 * 16777216);
  float* attn        = (float*)(ws + (size_t)3 * 16777216);

  const int Mrows = 4 * 2048, D = 1024;
  dim3 blk(256);
  dim3 ggrid(D / 128, Mrows / 128);   // (8, 64)

  gemm_bias_kernel<0><<<ggrid, blk, 0, stream>>>(query, Wq, bq, qh, Mrows, D, D);
  gemm_bias_kernel<0><<<ggrid, blk, 0, stream>>>(key_,  Wk, bk, kh, Mrows, D, D);
  gemm_bias_kernel<2><<<ggrid, blk, 0, stream>>>(value, Wv, bv, vt, Mrows, D, D);
  attn_kernel<<<dim3(2048 / 64, 64), blk, 0, stream>>>(qh, kh, vt, attn);
  gemm_bias_kernel<1><<<ggrid, blk, 0, stream>>>(attn, Wo, bo, (float*)d_out, Mrows, D, D);
}

// Round 2
// 332.688 us; speedup vs baseline: 1.4366x; 1.4366x over previous
//
#include <hip/hip_runtime.h>
#include <hip/hip_bf16.h>

typedef __attribute__((ext_vector_type(8))) short short8;
typedef __attribute__((ext_vector_type(4))) float f32x4;

#define DEVINL static __device__ __forceinline__

DEVINL unsigned short f2b(float f) {
  __hip_bfloat16 h = __float2bfloat16(f);
  return __builtin_bit_cast(unsigned short, h);
}

DEVINL float fexp2(float x) {
#if __has_builtin(__builtin_amdgcn_exp2f)
  return __builtin_amdgcn_exp2f(x);
#else
  float r; asm("v_exp_f32 %0, %1\n\ts_nop 0" : "=v"(r) : "v"(x)); return r;
#endif
}

DEVINL unsigned cvt_pk_bf16(float a, float b) {
  unsigned r;
  asm("v_cvt_pk_bf16_f32 %0, %1, %2" : "=v"(r) : "v"(a), "v"(b));
  return r;
}

// ============ GEMM + bias: C[M,N] = (A[M,K](f32) @ W[K,N](f32) + bias[N]) * oscale
// MODE 0: bf16 out, layout [B,H,S,64]   (Q,K split heads)
// MODE 1: f32  out, layout [M,N]        (final projection -> d_out)
// MODE 2: bf16 out, layout [B,H,64,S]   (V transposed heads, k-major for PV)
template<int MODE>
__global__ __launch_bounds__(256)
void gemm_bias_kernel(const float* __restrict__ A, const float* __restrict__ W,
                      const float* __restrict__ bias, void* __restrict__ outp,
                      int M, int N, int K, float oscale)
{
  constexpr int BK = 32;
  __shared__ __align__(16) unsigned short Asm[128][BK + 8];
  __shared__ __align__(16) unsigned short Bsm[128][BK + 8];

  const int tid = threadIdx.x;
  const int lane = tid & 63;
  const int wid = tid >> 6;
  const int l15 = lane & 15;
  const int lg  = lane >> 4;
  const long bm = (long)blockIdx.y * 128;
  const long bn = (long)blockIdx.x * 128;
  const int wm = (wid >> 1) * 64;
  const int wn = (wid & 1) * 64;

  f32x4 acc[4][4] = {};

  for (int kt = 0; kt < K; kt += BK) {
    #pragma unroll
    for (int i = 0; i < 4; ++i) {
      int task = tid + 256 * i;
      int r  = task >> 3;
      int c4 = (task & 7) << 2;
      const float4 v = *reinterpret_cast<const float4*>(A + (bm + r) * K + kt + c4);
      ushort4 h;
      h.x = f2b(v.x); h.y = f2b(v.y); h.z = f2b(v.z); h.w = f2b(v.w);
      *reinterpret_cast<ushort4*>(&Asm[r][c4]) = h;
    }
    #pragma unroll
    for (int i = 0; i < 4; ++i) {
      int task = tid + 256 * i;
      int n  = task & 127;
      int kq = (task >> 7) << 2;
      const float* wp = W + (long)(kt + kq) * N + bn + n;
      ushort4 h;
      h.x = f2b(wp[0]);
      h.y = f2b(wp[N]);
      h.z = f2b(wp[2 * N]);
      h.w = f2b(wp[3 * N]);
      *reinterpret_cast<ushort4*>(&Bsm[n][kq]) = h;
    }
    __syncthreads();

    short8 af[4], bf[4];
    #pragma unroll
    for (int m = 0; m < 4; ++m)
      af[m] = *reinterpret_cast<const short8*>(&Asm[wm + m*16 + l15][lg*8]);
    #pragma unroll
    for (int n = 0; n < 4; ++n)
      bf[n] = *reinterpret_cast<const short8*>(&Bsm[wn + n*16 + l15][lg*8]);
    #pragma unroll
    for (int m = 0; m < 4; ++m) {
      #pragma unroll
      for (int n = 0; n < 4; ++n)
        acc[m][n] = __builtin_amdgcn_mfma_f32_16x16x32_bf16(af[m], bf[n], acc[m][n], 0, 0, 0);
    }
    __syncthreads();
  }

  float bv[4];
  #pragma unroll
  for (int n = 0; n < 4; ++n) bv[n] = bias[bn + wn + n*16 + l15];

  if (MODE == 1) {
    float* out = (float*)outp;
    #pragma unroll
    for (int m = 0; m < 4; ++m) {
      #pragma unroll
      for (int r = 0; r < 4; ++r) {
        long row = bm + wm + m*16 + lg*4 + r;
        #pragma unroll
        for (int n = 0; n < 4; ++n)
          out[row * N + bn + wn + n*16 + l15] = (acc[m][n][r] + bv[n]) * oscale;
      }
    }
  } else if (MODE == 0) {
    unsigned short* out = (unsigned short*)outp;
    #pragma unroll
    for (int m = 0; m < 4; ++m) {
      #pragma unroll
      for (int r = 0; r < 4; ++r) {
        long row = bm + wm + m*16 + lg*4 + r;
        long b = row >> 11, s = row & 2047;
        #pragma unroll
        for (int n = 0; n < 4; ++n) {
          long col = bn + wn + n*16 + l15;
          long h = col >> 6, dk = col & 63;
          out[((((b << 4) + h) << 11) + s) * 64 + dk] = f2b((acc[m][n][r] + bv[n]) * oscale);
        }
      }
    }
  } else { // MODE 2: [B,H,64,S]
    unsigned short* out = (unsigned short*)outp;
    #pragma unroll
    for (int m = 0; m < 4; ++m) {
      long row0 = bm + wm + m*16 + lg*4;
      long b = row0 >> 11, s0 = row0 & 2047;
      #pragma unroll
      for (int n = 0; n < 4; ++n) {
        long col = bn + wn + n*16 + l15;
        long h = col >> 6, dk = col & 63;
        ushort4 hv;
        hv.x = f2b(acc[m][n][0] + bv[n]);
        hv.y = f2b(acc[m][n][1] + bv[n]);
        hv.z = f2b(acc[m][n][2] + bv[n]);
        hv.w = f2b(acc[m][n][3] + bv[n]);
        *reinterpret_cast<ushort4*>(&out[((((b << 4) + h) << 6) + dk) * 2048 + s0]) = hv;
      }
    }
  }
}

// ============ Flash attention, swapped-operand form ===========
// Q: [B,H,S,64] bf16 PRE-SCALED by 0.125*log2(e); K: [B,H,S,64]; Vth: [B,H,64,S]
// scores_exp2 = Q'K^T, doubled where |i-j|<=4; softmax via exp2; O = P V.
// Swapped: S^T = mfma(K, Q) so each lane owns one q-column; O^T = mfma(V^T, P^T).
__global__ __launch_bounds__(256)
void attn_kernel(const unsigned short* __restrict__ Q,
                 const unsigned short* __restrict__ Kh,
                 const unsigned short* __restrict__ Vth,
                 float* __restrict__ O)
{
  __shared__ __align__(16) unsigned short Ksm[64 * 64];       // XOR-swizzled [kv][d]
  __shared__ __align__(16) unsigned short Vsm[64][72];        // [d][kv], padded
  __shared__ __align__(16) unsigned short Psm[4][2][16][72];  // [wave][set][q][kv], padded

  const int tid = threadIdx.x;
  const int lane = tid & 63;
  const int w = tid >> 6;
  const int l15 = lane & 15;
  const int lg  = lane >> 4;
  const int bh = blockIdx.y;
  const int qb = blockIdx.x * 128;
  const long base = (long)bh * 2048 * 64;
  const int wq = qb + w * 32;            // wave's first q row

  // Q fragments in registers; set s covers q rows [wq+16s, wq+16s+16)
  short8 aq[2][2];
  #pragma unroll
  for (int s = 0; s < 2; ++s) {
    const unsigned short* qp = Q + base + (long)(wq + s*16 + l15) * 64 + lg*8;
    aq[s][0] = *reinterpret_cast<const short8*>(qp);
    aq[s][1] = *reinterpret_cast<const short8*>(qp + 32);
  }

  f32x4 oacc[2][4] = {};                 // [set][nd] : O^T frag, col q=l15, row d
  float mrun[2] = {-1e30f, -1e30f};
  float lrun[2] = {0.f, 0.f};

  for (int kvt = 0; kvt < 2048; kvt += 64) {
    // ---- stage K (XOR-swizzled rows) ----
    #pragma unroll
    for (int c = 0; c < 2; ++c) {
      int e = (tid + 256 * c) * 8;             // bf16 element offset in 64x64 tile
      int row = e >> 6;
      uint4 v = *reinterpret_cast<const uint4*>(Kh + base + (long)kvt * 64 + e);
      int dst = (e * 2) ^ ((row & 7) << 4);
      *reinterpret_cast<uint4*>(reinterpret_cast<char*>(Ksm) + dst) = v;
    }
    // ---- stage V^T tile rows ----
    {
      int dr = tid >> 2;
      int ch = (tid & 3) * 16;
      const unsigned short* vp = Vth + (long)bh * 64 * 2048 + (long)dr * 2048 + kvt + ch;
      uint4 v0 = *reinterpret_cast<const uint4*>(vp);
      uint4 v1 = *reinterpret_cast<const uint4*>(vp + 8);
      *reinterpret_cast<uint4*>(&Vsm[dr][ch]) = v0;
      *reinterpret_cast<uint4*>(&Vsm[dr][ch + 8]) = v1;
    }
    __syncthreads();

    // ---- fragment loads, shared across both q-sets ----
    short8 ak[4][2], av[4][2];
    #pragma unroll
    for (int n = 0; n < 4; ++n) {
      int row = n * 16 + l15;
      #pragma unroll
      for (int kc = 0; kc < 2; ++kc) {
        int src = (row * 128 + (kc * 32 + lg * 8) * 2) ^ ((row & 7) << 4);
        ak[n][kc] = *reinterpret_cast<const short8*>(reinterpret_cast<char*>(Ksm) + src);
        av[n][kc] = *reinterpret_cast<const short8*>(&Vsm[n * 16 + l15][kc * 32 + lg * 8]);
      }
    }

    const bool band_near = (kvt <= wq + 35) && (kvt + 67 >= wq);

    #pragma unroll
    for (int s = 0; s < 2; ++s) {
      // S^T = mfma(K, Q): lane holds col q=l15, rows kv = n*16 + lg*4 + r
      f32x4 st[4] = {};
      #pragma unroll
      for (int n = 0; n < 4; ++n) {
        st[n] = __builtin_amdgcn_mfma_f32_16x16x32_bf16(ak[n][0], aq[s][0], st[n], 0, 0, 0);
        st[n] = __builtin_amdgcn_mfma_f32_16x16x32_bf16(ak[n][1], aq[s][1], st[n], 0, 0, 0);
      }
      // band enhancement (x2 in exp2-scaled domain == x2 on raw score)
      if (band_near) {
        int qg = wq + s * 16 + l15;
        #pragma unroll
        for (int n = 0; n < 4; ++n) {
          #pragma unroll
          for (int r = 0; r < 4; ++r) {
            int d = qg - (kvt + n * 16 + lg * 4 + r);
            if (d >= -4 && d <= 4) st[n][r] *= 2.f;
          }
        }
      }
      // row max: in-lane tree + 2 cross-lane steps (4 lanes share q=l15)
      float a0 = fmaxf(fmaxf(st[0][0], st[0][1]), fmaxf(st[0][2], st[0][3]));
      float a1 = fmaxf(fmaxf(st[1][0], st[1][1]), fmaxf(st[1][2], st[1][3]));
      float a2 = fmaxf(fmaxf(st[2][0], st[2][1]), fmaxf(st[2][2], st[2][3]));
      float a3 = fmaxf(fmaxf(st[3][0], st[3][1]), fmaxf(st[3][2], st[3][3]));
      float pmax = fmaxf(fmaxf(a0, a1), fmaxf(a2, a3));
      pmax = fmaxf(pmax, __shfl_xor(pmax, 16));
      pmax = fmaxf(pmax, __shfl_xor(pmax, 32));
      // defer-max (T13): only rescale when tile max exceeds running max + 8
      if (pmax > mrun[s] + 8.f) {
        float corr = fexp2(mrun[s] - pmax);
        lrun[s] *= corr;
        #pragma unroll
        for (int nd = 0; nd < 4; ++nd)
          #pragma unroll
          for (int r = 0; r < 4; ++r) oacc[s][nd][r] *= corr;
        mrun[s] = pmax;
      }
      const float mloc = mrun[s];
      #pragma unroll
      for (int n = 0; n < 4; ++n)
        #pragma unroll
        for (int r = 0; r < 4; ++r) st[n][r] = fexp2(st[n][r] - mloc);
      float t0 = (st[0][0] + st[0][1]) + (st[0][2] + st[0][3]);
      float t1 = (st[1][0] + st[1][1]) + (st[1][2] + st[1][3]);
      float t2 = (st[2][0] + st[2][1]) + (st[2][2] + st[2][3]);
      float t3 = (st[3][0] + st[3][1]) + (st[3][2] + st[3][3]);
      float ts = (t0 + t1) + (t2 + t3);
      ts += __shfl_xor(ts, 16);
      ts += __shfl_xor(ts, 32);
      lrun[s] += ts;
      // P^T -> LDS: packed pair writes (kv pairs are contiguous in swapped layout)
      {
        unsigned short* pp = &Psm[w][s][l15][lg * 4];
        *reinterpret_cast<unsigned*>(pp +  0) = cvt_pk_bf16(st[0][0], st[0][1]);
        *reinterpret_cast<unsigned*>(pp +  2) = cvt_pk_bf16(st[0][2], st[0][3]);
        *reinterpret_cast<unsigned*>(pp + 16) = cvt_pk_bf16(st[1][0], st[1][1]);
        *reinterpret_cast<unsigned*>(pp + 18) = cvt_pk_bf16(st[1][2], st[1][3]);
        *reinterpret_cast<unsigned*>(pp + 32) = cvt_pk_bf16(st[2][0], st[2][1]);
        *reinterpret_cast<unsigned*>(pp + 34) = cvt_pk_bf16(st[2][2], st[2][3]);
        *reinterpret_cast<unsigned*>(pp + 48) = cvt_pk_bf16(st[3][0], st[3][1]);
        *reinterpret_cast<unsigned*>(pp + 50) = cvt_pk_bf16(st[3][2], st[3][3]);
      }
      // O^T += mfma(V^T, P^T)
      {
        short8 pf0 = *reinterpret_cast<const short8*>(&Psm[w][s][l15][lg * 8]);
        short8 pf1 = *reinterpret_cast<const short8*>(&Psm[w][s][l15][32 + lg * 8]);
        #pragma unroll
        for (int nd = 0; nd < 4; ++nd) {
          oacc[s][nd] = __builtin_amdgcn_mfma_f32_16x16x32_bf16(av[nd][0], pf0, oacc[s][nd], 0, 0, 0);
          oacc[s][nd] = __builtin_amdgcn_mfma_f32_16x16x32_bf16(av[nd][1], pf1, oacc[s][nd], 0, 0, 0);
        }
      }
    }
    __syncthreads();
  }

  // ---- epilogue: O^T frag -> O[B,S,1024] fp32, merged heads ----
  const int b = bh >> 4, h = bh & 15;
  #pragma unroll
  for (int s = 0; s < 2; ++s) {
    float inv = 1.f / lrun[s];
    int q = wq + s * 16 + l15;
    float* op = O + ((long)(b * 2048 + q) << 10) + h * 64;
    #pragma unroll
    for (int nd = 0; nd < 4; ++nd) {
      float4 ov;
      ov.x = oacc[s][nd][0] * inv;
      ov.y = oacc[s][nd][1] * inv;
      ov.z = oacc[s][nd][2] * inv;
      ov.w = oacc[s][nd][3] * inv;
      *reinterpret_cast<float4*>(op + nd * 16 + lg * 4) = ov;
    }
  }
}

extern "C" void kernel_launch(void* const* d_in, const int* in_sizes, int n_in,
                              void* d_out, int out_size, void* d_ws, size_t ws_size,
                              hipStream_t stream)
{
  const float* query = (const float*)d_in[0];
  const float* key_  = (const float*)d_in[1];
  const float* value = (const float*)d_in[2];
  const float* Wq = (const float*)d_in[3];
  const float* bq = (const float*)d_in[4];
  const float* Wk = (const float*)d_in[5];
  const float* bk = (const float*)d_in[6];
  const float* Wv = (const float*)d_in[7];
  const float* bv = (const float*)d_in[8];
  const float* Wo = (const float*)d_in[9];
  const float* bo = (const float*)d_in[10];

  char* ws = (char*)d_ws;
  unsigned short* qh = (unsigned short*)(ws);
  unsigned short* kh = (unsigned short*)(ws + (size_t)16777216);
  unsigned short* vt = (unsigned short*)(ws + (size_t)2 * 16777216);
  float* attn        = (float*)(ws + (size_t)3 * 16777216);

  const int Mrows = 4 * 2048, D = 1024;
  dim3 blk(256);
  dim3 ggrid(D / 128, Mrows / 128);

  // Q pre-scaled by 1/sqrt(64) * log2(e) so attention works in exp2 domain
  const float QSCALE = 0.125f * 1.44269504088896340736f;

  gemm_bias_kernel<0><<<ggrid, blk, 0, stream>>>(query, Wq, bq, qh, Mrows, D, D, QSCALE);
  gemm_bias_kernel<0><<<ggrid, blk, 0, stream>>>(key_,  Wk, bk, kh, Mrows, D, D, 1.f);
  gemm_bias_kernel<2><<<ggrid, blk, 0, stream>>>(value, Wv, bv, vt, Mrows, D, D, 1.f);
  attn_kernel<<<dim3(2048 / 128, 64), blk, 0, stream>>>(qh, kh, vt, attn);
  gemm_bias_kernel<1><<<ggrid, blk, 0, stream>>>(attn, Wo, bo, (float*)d_out, Mrows, D, D, 1.f);
}

// Round 3
// 291.877 us; speedup vs baseline: 1.6375x; 1.1398x over previous
//
#include <hip/hip_runtime.h>
#include <hip/hip_bf16.h>

typedef __attribute__((ext_vector_type(8))) short short8;
typedef __attribute__((ext_vector_type(4))) float f32x4;
typedef __attribute__((ext_vector_type(16))) float f32x16;

#define DEVINL static __device__ __forceinline__

DEVINL unsigned short f2b(float f) {
  __hip_bfloat16 h = __float2bfloat16(f);
  return __builtin_bit_cast(unsigned short, h);
}

DEVINL float fexp2(float x) {
#if __has_builtin(__builtin_amdgcn_exp2f)
  return __builtin_amdgcn_exp2f(x);
#else
  float r; asm("v_exp_f32 %0, %1\n\ts_nop 0" : "=v"(r) : "v"(x)); return r;
#endif
}

DEVINL unsigned cvt_pk_bf16(float a, float b) {
  unsigned r;
  asm("v_cvt_pk_bf16_f32 %0, %1, %2" : "=v"(r) : "v"(a), "v"(b));
  return r;
}

// ============ GEMM + bias: C[M,N] = (A[M,K](f32) @ W[K,N](f32) + bias[N]) * oscale
// MODE 0: bf16 out, layout [B,H,S,64]   (Q,K split heads)
// MODE 1: f32  out, layout [M,N]        (final projection -> d_out)
// MODE 2: bf16 out, layout [B,H,64,S]   (V transposed heads, k-major for PV)
template<int MODE>
__global__ __launch_bounds__(256)
void gemm_bias_kernel(const float* __restrict__ A, const float* __restrict__ W,
                      const float* __restrict__ bias, void* __restrict__ outp,
                      int M, int N, int K, float oscale)
{
  constexpr int BK = 32;
  __shared__ __align__(16) unsigned short Asm[128][BK + 8];
  __shared__ __align__(16) unsigned short Bsm[128][BK + 8];

  const int tid = threadIdx.x;
  const int lane = tid & 63;
  const int wid = tid >> 6;
  const int l15 = lane & 15;
  const int lg  = lane >> 4;
  const long bm = (long)blockIdx.y * 128;
  const long bn = (long)blockIdx.x * 128;
  const int wm = (wid >> 1) * 64;
  const int wn = (wid & 1) * 64;

  f32x4 acc[4][4] = {};

  for (int kt = 0; kt < K; kt += BK) {
    #pragma unroll
    for (int i = 0; i < 4; ++i) {
      int task = tid + 256 * i;
      int r  = task >> 3;
      int c4 = (task & 7) << 2;
      const float4 v = *reinterpret_cast<const float4*>(A + (bm + r) * K + kt + c4);
      ushort4 h;
      h.x = f2b(v.x); h.y = f2b(v.y); h.z = f2b(v.z); h.w = f2b(v.w);
      *reinterpret_cast<ushort4*>(&Asm[r][c4]) = h;
    }
    #pragma unroll
    for (int i = 0; i < 4; ++i) {
      int task = tid + 256 * i;
      int n  = task & 127;
      int kq = (task >> 7) << 2;
      const float* wp = W + (long)(kt + kq) * N + bn + n;
      ushort4 h;
      h.x = f2b(wp[0]);
      h.y = f2b(wp[N]);
      h.z = f2b(wp[2 * N]);
      h.w = f2b(wp[3 * N]);
      *reinterpret_cast<ushort4*>(&Bsm[n][kq]) = h;
    }
    __syncthreads();

    short8 af[4], bf[4];
    #pragma unroll
    for (int m = 0; m < 4; ++m)
      af[m] = *reinterpret_cast<const short8*>(&Asm[wm + m*16 + l15][lg*8]);
    #pragma unroll
    for (int n = 0; n < 4; ++n)
      bf[n] = *reinterpret_cast<const short8*>(&Bsm[wn + n*16 + l15][lg*8]);
    #pragma unroll
    for (int m = 0; m < 4; ++m) {
      #pragma unroll
      for (int n = 0; n < 4; ++n)
        acc[m][n] = __builtin_amdgcn_mfma_f32_16x16x32_bf16(af[m], bf[n], acc[m][n], 0, 0, 0);
    }
    __syncthreads();
  }

  float bv[4];
  #pragma unroll
  for (int n = 0; n < 4; ++n) bv[n] = bias[bn + wn + n*16 + l15];

  if (MODE == 1) {
    float* out = (float*)outp;
    #pragma unroll
    for (int m = 0; m < 4; ++m) {
      #pragma unroll
      for (int r = 0; r < 4; ++r) {
        long row = bm + wm + m*16 + lg*4 + r;
        #pragma unroll
        for (int n = 0; n < 4; ++n)
          out[row * N + bn + wn + n*16 + l15] = (acc[m][n][r] + bv[n]) * oscale;
      }
    }
  } else if (MODE == 0) {
    unsigned short* out = (unsigned short*)outp;
    #pragma unroll
    for (int m = 0; m < 4; ++m) {
      #pragma unroll
      for (int r = 0; r < 4; ++r) {
        long row = bm + wm + m*16 + lg*4 + r;
        long b = row >> 11, s = row & 2047;
        #pragma unroll
        for (int n = 0; n < 4; ++n) {
          long col = bn + wn + n*16 + l15;
          long h = col >> 6, dk = col & 63;
          out[((((b << 4) + h) << 11) + s) * 64 + dk] = f2b((acc[m][n][r] + bv[n]) * oscale);
        }
      }
    }
  } else { // MODE 2: [B,H,64,S]
    unsigned short* out = (unsigned short*)outp;
    #pragma unroll
    for (int m = 0; m < 4; ++m) {
      long row0 = bm + wm + m*16 + lg*4;
      long b = row0 >> 11, s0 = row0 & 2047;
      #pragma unroll
      for (int n = 0; n < 4; ++n) {
        long col = bn + wn + n*16 + l15;
        long h = col >> 6, dk = col & 63;
        ushort4 hv;
        hv.x = f2b(acc[m][n][0] + bv[n]);
        hv.y = f2b(acc[m][n][1] + bv[n]);
        hv.z = f2b(acc[m][n][2] + bv[n]);
        hv.w = f2b(acc[m][n][3] + bv[n]);
        *reinterpret_cast<ushort4*>(&out[((((b << 4) + h) << 6) + dk) * 2048 + s0]) = hv;
      }
    }
  }
}

// ============ Flash attention: 32x32 MFMA, in-register P, XOR-swizzled K/V ===
// Q: [B,H,S,64] bf16 PRE-SCALED by 0.125*log2(e); K: [B,H,S,64]; Vth: [B,H,64,S]
// Swapped ops: S^T = mfma(K, Q) (lane owns q-col = lane&31);
// P^T kept in registers via cvt_pk + shfl_xor(32); O^T = mfma(V^T, P^T).
// LDS tiles (64kv x 64d bf16, 8KB each) XOR-swizzled: byte ^= (row&7)<<4.
__global__ __launch_bounds__(512)
void attn_kernel(const unsigned short* __restrict__ Q,
                 const unsigned short* __restrict__ Kh,
                 const unsigned short* __restrict__ Vth,
                 float* __restrict__ O)
{
  __shared__ __align__(16) char lds[16384];   // K swz at [0,8K), V swz at [8K,16K)

  const int tid = threadIdx.x;
  const int lane = tid & 63;
  const int w = tid >> 6;              // wave 0..7
  const int l31 = lane & 31;
  const int hi  = lane >> 5;
  const int r7  = l31 & 7;
  const int bh = blockIdx.y;           // b*16 + h
  const int wq = blockIdx.x * 256 + w * 32;
  const long base  = (long)bh * 2048 * 64;
  const long vbase = (long)bh * 64 * 2048;

  // Q B-fragments: q = wq + l31, d = sl*16 + hi*8 + j
  short8 aq[4];
  {
    const unsigned short* qp = Q + base + (long)(wq + l31) * 64 + hi * 8;
    #pragma unroll
    for (int sl = 0; sl < 4; ++sl)
      aq[sl] = *reinterpret_cast<const short8*>(qp + sl * 16);
  }

  // staging: 512 threads x 16B cover one 64x64 bf16 tile
  const int srow = tid >> 3;               // 0..63
  const int sdst = (srow * 128 + (tid & 7) * 16) ^ ((srow & 7) << 4);
  const unsigned short* kgp = Kh + base + srow * 64 + (tid & 7) * 8;
  const unsigned short* vgp = Vth + vbase + (long)srow * 2048 + (tid & 7) * 8;

  uint4 kreg = *reinterpret_cast<const uint4*>(kgp);
  uint4 vreg = *reinterpret_cast<const uint4*>(vgp);

  f32x16 oacc0 = {}, oacc1 = {};
  float mrun = -1e30f, lrun = 0.f;

  for (int kvt = 0; kvt < 2048; kvt += 64) {
    __syncthreads();                         // all waves done reading prev tile
    *reinterpret_cast<uint4*>(lds + sdst) = kreg;
    *reinterpret_cast<uint4*>(lds + 8192 + sdst) = vreg;
    __syncthreads();
    if (kvt + 64 < 2048) {                   // T14: issue next-tile loads now
      kreg = *reinterpret_cast<const uint4*>(kgp + (kvt + 64) * 64);
      vreg = *reinterpret_cast<const uint4*>(vgp + (kvt + 64));
    }

    // ---- S^T = K @ Q^T (32x32x16), nb=0: kv rows 0-31, nb=1: 32-63 ----
    f32x16 st0 = {}, st1 = {};
    #pragma unroll
    for (int sl = 0; sl < 4; ++sl) {
      const int slot = (((sl * 2 + hi) ^ r7) << 4);
      short8 ak0 = *reinterpret_cast<const short8*>(lds + l31 * 128 + slot);
      short8 ak1 = *reinterpret_cast<const short8*>(lds + (32 + l31) * 128 + slot);
      st0 = __builtin_amdgcn_mfma_f32_32x32x16_bf16(ak0, aq[sl], st0, 0, 0, 0);
      st1 = __builtin_amdgcn_mfma_f32_32x32x16_bf16(ak1, aq[sl], st1, 0, 0, 0);
    }

    // ---- banded enhancement: x2 where |q - kv| <= 4 (near-diagonal tiles) ----
    if ((kvt <= wq + 35) && (kvt + 67 >= wq)) {
      const int db0 = wq + l31 - kvt - 4 * hi;
      #pragma unroll
      for (int r = 0; r < 16; ++r) {
        const int rr = (r & 3) + 8 * (r >> 2);
        int d0 = db0 - rr;
        int d1 = db0 - 32 - rr;
        if (d0 >= -4 && d0 <= 4) st0[r] *= 2.f;
        if (d1 >= -4 && d1 <= 4) st1[r] *= 2.f;
      }
    }

    // ---- row max: balanced in-lane tree + 1 cross-lane step ----
    float tm[16];
    #pragma unroll
    for (int r = 0; r < 16; ++r) tm[r] = fmaxf(st0[r], st1[r]);
    #pragma unroll
    for (int s2 = 8; s2 >= 1; s2 >>= 1)
      #pragma unroll
      for (int r = 0; r < s2; ++r) tm[r] = fmaxf(tm[r], tm[r + s2]);
    float pmax = fmaxf(tm[0], __shfl_xor(tm[0], 32));

    // ---- defer-max (T13, THR=8) ----
    if (pmax > mrun + 8.f) {
      float corr = fexp2(mrun - pmax);
      lrun *= corr;
      #pragma unroll
      for (int r = 0; r < 16; ++r) { oacc0[r] *= corr; oacc1[r] *= corr; }
      mrun = pmax;
    }

    // ---- exp2 + row sum ----
    #pragma unroll
    for (int r = 0; r < 16; ++r) {
      st0[r] = fexp2(st0[r] - mrun);
      st1[r] = fexp2(st1[r] - mrun);
    }
    float ts[16];
    #pragma unroll
    for (int r = 0; r < 16; ++r) ts[r] = st0[r] + st1[r];
    #pragma unroll
    for (int s2 = 8; s2 >= 1; s2 >>= 1)
      #pragma unroll
      for (int r = 0; r < s2; ++r) ts[r] += ts[r + s2];
    lrun += ts[0] + __shfl_xor(ts[0], 32);

    // ---- P^T -> bf16 words, in-register redistribution (T12 structure) ----
    // own[nb][p]: bf16 pair at kv = nb*32 + 8*(p>>1) + 4*hi + 2*(p&1)
    unsigned own0[8], own1[8], rcv0[8], rcv1[8];
    #pragma unroll
    for (int p = 0; p < 8; ++p) {
      own0[p] = cvt_pk_bf16(st0[2 * p], st0[2 * p + 1]);
      own1[p] = cvt_pk_bf16(st1[2 * p], st1[2 * p + 1]);
    }
    #pragma unroll
    for (int p = 0; p < 8; ++p) {
      rcv0[p] = __shfl_xor(own0[p], 32);
      rcv1[p] = __shfl_xor(own1[p], 32);
    }

    // ---- O^T += V^T @ P^T : per kv-slice sl (nb = sl>>1, cc = sl&1) ----
    #pragma unroll
    for (int sl = 0; sl < 4; ++sl) {
      const unsigned* ow = (sl < 2) ? own0 : own1;
      const unsigned* rv = (sl < 2) ? rcv0 : rcv1;
      const int cc = sl & 1;
      // B-frag (col q = l31, k = sl*16 + hi*8 + j), words kv-pair ascending:
      uint4 pw;
      pw.x = hi ? rv[(2 * cc + 1) * 2 + 0] : ow[(2 * cc) * 2 + 0];
      pw.y = hi ? rv[(2 * cc + 1) * 2 + 1] : ow[(2 * cc) * 2 + 1];
      pw.z = hi ? ow[(2 * cc + 1) * 2 + 0] : rv[(2 * cc) * 2 + 0];
      pw.w = hi ? ow[(2 * cc + 1) * 2 + 1] : rv[(2 * cc) * 2 + 1];
      short8 pf = __builtin_bit_cast(short8, pw);
      const int slot = (((sl * 2 + hi) ^ r7) << 4);
      short8 av0 = *reinterpret_cast<const short8*>(lds + 8192 + l31 * 128 + slot);
      short8 av1 = *reinterpret_cast<const short8*>(lds + 8192 + (32 + l31) * 128 + slot);
      oacc0 = __builtin_amdgcn_mfma_f32_32x32x16_bf16(av0, pf, oacc0, 0, 0, 0);
      oacc1 = __builtin_amdgcn_mfma_f32_32x32x16_bf16(av1, pf, oacc1, 0, 0, 0);
    }
  }

  // ---- epilogue: O^T frag -> O[B,S,1024] fp32 (heads merged) ----
  const int b = bh >> 4, h = bh & 15;
  const float inv = 1.f / lrun;
  float* op = O + ((long)(b * 2048 + wq + l31) << 10) + h * 64 + 4 * hi;
  #pragma unroll
  for (int r = 0; r < 16; ++r) {
    const int d = (r & 3) + 8 * (r >> 2);
    op[d]      = oacc0[r] * inv;
    op[d + 32] = oacc1[r] * inv;
  }
}

extern "C" void kernel_launch(void* const* d_in, const int* in_sizes, int n_in,
                              void* d_out, int out_size, void* d_ws, size_t ws_size,
                              hipStream_t stream)
{
  const float* query = (const float*)d_in[0];
  const float* key_  = (const float*)d_in[1];
  const float* value = (const float*)d_in[2];
  const float* Wq = (const float*)d_in[3];
  const float* bq = (const float*)d_in[4];
  const float* Wk = (const float*)d_in[5];
  const float* bk = (const float*)d_in[6];
  const float* Wv = (const float*)d_in[7];
  const float* bv = (const float*)d_in[8];
  const float* Wo = (const float*)d_in[9];
  const float* bo = (const float*)d_in[10];

  char* ws = (char*)d_ws;
  unsigned short* qh = (unsigned short*)(ws);
  unsigned short* kh = (unsigned short*)(ws + (size_t)16777216);
  unsigned short* vt = (unsigned short*)(ws + (size_t)2 * 16777216);
  float* attn        = (float*)(ws + (size_t)3 * 16777216);

  const int Mrows = 4 * 2048, D = 1024;
  dim3 blk(256);
  dim3 ggrid(D / 128, Mrows / 128);

  // Q pre-scaled by 1/sqrt(64) * log2(e) so attention works in exp2 domain
  const float QSCALE = 0.125f * 1.44269504088896340736f;

  gemm_bias_kernel<0><<<ggrid, blk, 0, stream>>>(query, Wq, bq, qh, Mrows, D, D, QSCALE);
  gemm_bias_kernel<0><<<ggrid, blk, 0, stream>>>(key_,  Wk, bk, kh, Mrows, D, D, 1.f);
  gemm_bias_kernel<2><<<ggrid, blk, 0, stream>>>(value, Wv, bv, vt, Mrows, D, D, 1.f);
  attn_kernel<<<dim3(2048 / 256, 64), 512, 0, stream>>>(qh, kh, vt, attn);
  gemm_bias_kernel<1><<<ggrid, blk, 0, stream>>>(attn, Wo, bo, (float*)d_out, Mrows, D, D, 1.f);
}